// Round 1
// baseline (304.635 us; speedup 1.0000x reference)
//
#include <hip/hip_runtime.h>
#include <math.h>

// Problem constants (match reference)
#define BDIM 64
#define NN   2048
#define EE   8192
#define LL   50
#define DD   128
#define RR   5
#define NBASES 4
#define H3   192

#define TILE 2048

// ---------------------------------------------------------------------------
// Precompute W[r][i][o] = sum_b comp[r][b] * bases[b][i][o]   (5 x 128 x 128)
// ---------------------------------------------------------------------------
__global__ __launch_bounds__(256) void precompute_W(const float* __restrict__ comp,
                                                    const float* __restrict__ bases,
                                                    float* __restrict__ W) {
    int idx = blockIdx.x * 256 + threadIdx.x;
    if (idx >= RR * DD * DD) return;
    int r  = idx / (DD * DD);
    int io = idx % (DD * DD);
    float acc = 0.f;
#pragma unroll
    for (int b = 0; b < NBASES; ++b)
        acc += comp[r * NBASES + b] * bases[b * DD * DD + io];
    W[idx] = acc;
}

// ---------------------------------------------------------------------------
// Precompute A[i][j] = sum_d wq[i][d] * wk[j][d]   (128 x 128), d over 192
// ---------------------------------------------------------------------------
__global__ __launch_bounds__(256) void precompute_A(const float* __restrict__ wq,
                                                    const float* __restrict__ wk,
                                                    float* __restrict__ A) {
    int idx = blockIdx.x * 256 + threadIdx.x;
    if (idx >= DD * DD) return;
    int i = idx >> 7, j = idx & 127;
    float acc = 0.f;
    for (int d = 0; d < H3; ++d)
        acc += wq[i * H3 + d] * wk[j * H3 + d];
    A[idx] = acc;
}

// ---------------------------------------------------------------------------
// Precompute va[i] = sum_d wv[i][d]*attn_w[d],  vf[i] = sum_d wv[i][d]*fc_w[d]
// ---------------------------------------------------------------------------
__global__ __launch_bounds__(128) void precompute_v(const float* __restrict__ wv,
                                                    const float* __restrict__ attn_w,
                                                    const float* __restrict__ fc_w,
                                                    float* __restrict__ va,
                                                    float* __restrict__ vf) {
    int i = threadIdx.x;
    if (i < DD) {
        float a = 0.f, f = 0.f;
        for (int d = 0; d < H3; ++d) {
            float w = wv[i * H3 + d];
            a += w * attn_w[d];
            f += w * fc_w[d];
        }
        va[i] = a;
        vf[i] = f;
    }
}

// ---------------------------------------------------------------------------
// build_X: one block per (b, l). Compute x_upd at node = sent_ids[b][l]:
//   X[b][l] = root_b + x_node @ root_w + sum_r (1/cnt_r) * (sum_{e: tgt=node, et=r} x_src) @ W[r]
// ---------------------------------------------------------------------------
__global__ __launch_bounds__(256) void build_X(const float* __restrict__ emb,
                                               const float* __restrict__ W,
                                               const float* __restrict__ root_w,
                                               const float* __restrict__ root_b,
                                               const int* __restrict__ node_ids,
                                               const int* __restrict__ edge_index,
                                               const int* __restrict__ edge_type,
                                               const int* __restrict__ sent_ids,
                                               float* __restrict__ Xws) {
    int bl = blockIdx.x;                 // b*LL + l
    int b  = bl / LL;
    int t  = threadIdx.x;
    int node = sent_ids[bl];

    const int* src_arr = edge_index + (size_t)b * 2 * EE;
    const int* tgt_arr = src_arr + EE;
    const int* et_arr  = edge_type + (size_t)b * EE;
    const int* nid     = node_ids + (size_t)b * NN;

    __shared__ float xsum[RR][DD];
    __shared__ float xnode[DD];
    __shared__ int   cnt[RR];
    __shared__ int   elist[TILE];
    __shared__ int   nmatch;

    for (int i = t; i < RR * DD; i += 256) ((float*)xsum)[i] = 0.f;
    if (t < RR) cnt[t] = 0;
    if (t < DD) xnode[t] = emb[(size_t)nid[node] * DD + t];
    __syncthreads();

    for (int base = 0; base < EE; base += TILE) {
        if (t == 0) nmatch = 0;
        __syncthreads();
#pragma unroll
        for (int e = base + t; e < base + TILE; e += 256) {
            if (tgt_arr[e] == node) {
                int m = atomicAdd(&nmatch, 1);
                elist[m] = e;
            }
        }
        __syncthreads();
        int nm = nmatch;
        for (int m = 0; m < nm; ++m) {
            int e = elist[m];
            int r = et_arr[e];
            int s = src_arr[e];
            if (t == 0) cnt[r] += 1;
            if (t < DD) xsum[r][t] += emb[(size_t)nid[s] * DD + t];
        }
        __syncthreads();
    }

    if (t < DD) {
        int o = t;
        float acc = root_b[o];
        float a = 0.f;
#pragma unroll 4
        for (int i = 0; i < DD; ++i) a += xnode[i] * root_w[i * DD + o];
        acc += a;
        for (int r = 0; r < RR; ++r) {
            int c = cnt[r];
            if (c > 0) {
                const float* Wr = W + r * DD * DD;
                float a2 = 0.f;
#pragma unroll 4
                for (int i = 0; i < DD; ++i) a2 += xsum[r][i] * Wr[i * DD + o];
                acc += a2 / (float)c;
            }
        }
        Xws[(size_t)bl * DD + o] = acc;
    }
}

// ---------------------------------------------------------------------------
// Attention: one block per batch b.
//   XA = X @ A;  S = softmax(XA X^T / sqrt(192))
//   p[m] = X[m].va ; q[m] = X[m].vf
//   attn[l] = S[l].p + attn_b ; g[l] = S[l].q
//   out[b] = sigmoid( sum_l attn[l]*g[l] + fc_b )
// ---------------------------------------------------------------------------
__global__ __launch_bounds__(256) void attn_kernel(const float* __restrict__ Xws,
                                                   const float* __restrict__ A,
                                                   const float* __restrict__ va,
                                                   const float* __restrict__ vf,
                                                   const float* __restrict__ attn_b,
                                                   const float* __restrict__ fc_b,
                                                   float* __restrict__ out) {
    __shared__ float Xs[LL][DD + 1];   // +1 pad: kill stride-128 bank conflicts
    __shared__ float XA[LL][DD + 1];
    __shared__ float S[LL][LL];
    __shared__ float pv[LL], qv[LL], av[LL], gv[LL];

    int t = threadIdx.x;
    int b = blockIdx.x;
    const float* Xb = Xws + (size_t)b * LL * DD;

    for (int i = t; i < LL * DD; i += 256)
        Xs[i / DD][i % DD] = Xb[i];
    __syncthreads();

    // XA = X @ A
    for (int i = t; i < LL * DD; i += 256) {
        int l = i / DD, o = i % DD;
        float acc = 0.f;
#pragma unroll 4
        for (int k = 0; k < DD; ++k) acc += Xs[l][k] * A[k * DD + o];
        XA[l][o] = acc;
    }
    // p, q
    if (t < 2 * LL) {
        int m = (t < LL) ? t : (t - LL);
        const float* w = (t < LL) ? va : vf;
        float acc = 0.f;
#pragma unroll 4
        for (int k = 0; k < DD; ++k) acc += Xs[m][k] * w[k];
        if (t < LL) pv[m] = acc; else qv[m] = acc;
    }
    __syncthreads();

    const float scale = 0.07216878364870322f;  // 1/sqrt(192)
    for (int i = t; i < LL * LL; i += 256) {
        int l = i / LL, m = i % LL;
        float acc = 0.f;
#pragma unroll 4
        for (int k = 0; k < DD; ++k) acc += XA[l][k] * Xs[m][k];
        S[l][m] = acc * scale;
    }
    __syncthreads();

    if (t < LL) {
        float mx = -1e30f;
        for (int m = 0; m < LL; ++m) mx = fmaxf(mx, S[t][m]);
        float sum = 0.f;
        for (int m = 0; m < LL; ++m) {
            float e = expf(S[t][m] - mx);
            S[t][m] = e;
            sum += e;
        }
        float inv = 1.f / sum;
        float a = 0.f, g = 0.f;
        for (int m = 0; m < LL; ++m) {
            float sm = S[t][m] * inv;
            a += sm * pv[m];
            g += sm * qv[m];
        }
        av[t] = a + attn_b[0];
        gv[t] = g;
    }
    __syncthreads();

    if (t == 0) {
        float acc = fc_b[0];
        for (int l = 0; l < LL; ++l) acc += av[l] * gv[l];
        out[b] = 1.f / (1.f + expf(-acc));
    }
}

// ---------------------------------------------------------------------------
extern "C" void kernel_launch(void* const* d_in, const int* in_sizes, int n_in,
                              void* d_out, int out_size, void* d_ws, size_t ws_size,
                              hipStream_t stream) {
    const float* emb     = (const float*)d_in[0];
    const float* bases   = (const float*)d_in[1];
    const float* comp    = (const float*)d_in[2];
    const float* root_w  = (const float*)d_in[3];
    const float* root_b  = (const float*)d_in[4];
    const float* wq      = (const float*)d_in[5];
    const float* wk      = (const float*)d_in[6];
    const float* wv      = (const float*)d_in[7];
    const float* attn_w  = (const float*)d_in[8];
    const float* attn_b  = (const float*)d_in[9];
    const float* fc_w    = (const float*)d_in[10];
    const float* fc_b    = (const float*)d_in[11];
    const int* node_ids  = (const int*)d_in[12];
    const int* edge_index= (const int*)d_in[13];
    const int* edge_type = (const int*)d_in[14];
    const int* sent_ids  = (const int*)d_in[15];
    float* out = (float*)d_out;

    float* ws = (float*)d_ws;
    float* W   = ws;                    // 5*128*128 = 81920
    float* A   = ws + 81920;            // 128*128   = 16384
    float* va  = ws + 98304;            // 128
    float* vf  = ws + 98432;            // 128
    float* Xws = ws + 98560;            // 64*50*128 = 409600

    hipLaunchKernelGGL(precompute_W, dim3((RR * DD * DD + 255) / 256), dim3(256), 0, stream,
                       comp, bases, W);
    hipLaunchKernelGGL(precompute_A, dim3((DD * DD + 255) / 256), dim3(256), 0, stream,
                       wq, wk, A);
    hipLaunchKernelGGL(precompute_v, dim3(1), dim3(128), 0, stream,
                       wv, attn_w, fc_w, va, vf);
    hipLaunchKernelGGL(build_X, dim3(BDIM * LL), dim3(256), 0, stream,
                       emb, W, root_w, root_b, node_ids, edge_index, edge_type, sent_ids, Xws);
    hipLaunchKernelGGL(attn_kernel, dim3(BDIM), dim3(256), 0, stream,
                       Xws, A, va, vf, attn_b, fc_b, out);
}

// Round 2
// 245.042 us; speedup vs baseline: 1.2432x; 1.2432x over previous
//
#include <hip/hip_runtime.h>
#include <math.h>

#define BDIM 64
#define NN   2048
#define EE   8192
#define LL   50
#define DD   128
#define RR   5
#define NBASES 4
#define H3   192
#define RECCAP 1024

// ---------------------------------------------------------------------------
// W[r][i][o] = sum_b comp[r][b] * bases[b][i][o]
// ---------------------------------------------------------------------------
__global__ __launch_bounds__(256) void precompute_W(const float* __restrict__ comp,
                                                    const float* __restrict__ bases,
                                                    float* __restrict__ W) {
    int idx = blockIdx.x * 256 + threadIdx.x;
    if (idx >= RR * DD * DD) return;
    int r  = idx / (DD * DD);
    int io = idx % (DD * DD);
    float acc = 0.f;
#pragma unroll
    for (int b = 0; b < NBASES; ++b)
        acc += comp[r * NBASES + b] * bases[b * DD * DD + io];
    W[idx] = acc;
}

// ---------------------------------------------------------------------------
// A[i][j] = sum_d wq[i][d] * wk[j][d]  — one block per row i, thread j streams
// its contiguous wk row via float4.
// ---------------------------------------------------------------------------
__global__ __launch_bounds__(128) void precompute_A(const float* __restrict__ wq,
                                                    const float* __restrict__ wk,
                                                    float* __restrict__ A) {
    int i = blockIdx.x;
    int j = threadIdx.x;
    __shared__ float wqs[H3];
    for (int d = j; d < H3; d += 128) wqs[d] = wq[i * H3 + d];
    __syncthreads();
    const float4* wkr = (const float4*)(wk + j * H3);
    float acc = 0.f;
#pragma unroll
    for (int d4 = 0; d4 < H3 / 4; ++d4) {
        float4 v = wkr[d4];
        acc += wqs[4 * d4 + 0] * v.x + wqs[4 * d4 + 1] * v.y
             + wqs[4 * d4 + 2] * v.z + wqs[4 * d4 + 3] * v.w;
    }
    A[i * DD + j] = acc;
}

// ---------------------------------------------------------------------------
// va[i] = wv[i]·attn_w ; vf[i] = wv[i]·fc_w ; zero the per-batch accumulators
// ---------------------------------------------------------------------------
__global__ __launch_bounds__(128) void precompute_v(const float* __restrict__ wv,
                                                    const float* __restrict__ attn_w,
                                                    const float* __restrict__ fc_w,
                                                    float* __restrict__ va,
                                                    float* __restrict__ vf,
                                                    float* __restrict__ acc) {
    int i = threadIdx.x;
    if (i < BDIM) acc[i] = 0.f;
    const float4* wr = (const float4*)(wv + i * H3);
    float a = 0.f, f = 0.f;
#pragma unroll
    for (int d4 = 0; d4 < H3 / 4; ++d4) {
        float4 v = wr[d4];
        a += v.x * attn_w[4 * d4 + 0] + v.y * attn_w[4 * d4 + 1]
           + v.z * attn_w[4 * d4 + 2] + v.w * attn_w[4 * d4 + 3];
        f += v.x * fc_w[4 * d4 + 0] + v.y * fc_w[4 * d4 + 1]
           + v.z * fc_w[4 * d4 + 2] + v.w * fc_w[4 * d4 + 3];
    }
    va[i] = a;
    vf[i] = f;
}

// ---------------------------------------------------------------------------
// matchscan: one block per batch. Build node->l map in LDS, scan edges once,
// emit packed records (l<<14 | r<<11 | src) + per-(l,r) counts.
// ---------------------------------------------------------------------------
__global__ __launch_bounds__(256) void matchscan(const int* __restrict__ edge_index,
                                                 const int* __restrict__ edge_type,
                                                 const int* __restrict__ sent_ids,
                                                 int* __restrict__ rep,
                                                 int* __restrict__ nrec,
                                                 int* __restrict__ cnts,
                                                 int* __restrict__ recbuf) {
    int b = blockIdx.x, t = threadIdx.x;
    __shared__ int mark[NN];
    __shared__ int scnt[LL * RR];
    __shared__ int lcnt;
    for (int i = t; i < NN; i += 256) mark[i] = -1;
    for (int i = t; i < LL * RR; i += 256) scnt[i] = 0;
    if (t == 0) lcnt = 0;
    __syncthreads();
    const int* sb = sent_ids + b * LL;
    if (t < LL) mark[sb[t]] = t;   // duplicates: arbitrary winner, consistent below
    __syncthreads();
    if (t < LL) rep[b * LL + t] = mark[sb[t]];

    const int* src_arr = edge_index + (size_t)b * 2 * EE;
    const int* tgt_arr = src_arr + EE;
    const int* et_arr  = edge_type + (size_t)b * EE;
    const int4* tgt4 = (const int4*)tgt_arr;
    for (int i4 = t; i4 < EE / 4; i4 += 256) {
        int4 v = tgt4[i4];
        int e0 = 4 * i4;
        int ls0 = mark[v.x], ls1 = mark[v.y], ls2 = mark[v.z], ls3 = mark[v.w];
        int lv[4] = {ls0, ls1, ls2, ls3};
#pragma unroll
        for (int k = 0; k < 4; ++k) {
            int l = lv[k];
            if (l >= 0) {
                int e = e0 + k;
                int r = et_arr[e];
                int s = src_arr[e];
                int pos = atomicAdd(&lcnt, 1);
                if (pos < RECCAP) recbuf[b * RECCAP + pos] = (l << 14) | (r << 11) | s;
                atomicAdd(&scnt[l * RR + r], 1);
            }
        }
    }
    __syncthreads();
    for (int i = t; i < LL * RR; i += 256) cnts[b * LL * RR + i] = scnt[i];
    if (t == 0) nrec[b] = (lcnt < RECCAP) ? lcnt : RECCAP;
}

// ---------------------------------------------------------------------------
// build_X: one block per (b,l). Process only matching records; then fused
// epilogue: x row, XA row, p = x·va, q = x·vf.
// ---------------------------------------------------------------------------
__global__ __launch_bounds__(256) void build_X(const float* __restrict__ emb,
                                               const float* __restrict__ W,
                                               const float* __restrict__ root_w,
                                               const float* __restrict__ root_b,
                                               const float* __restrict__ A,
                                               const float* __restrict__ va,
                                               const float* __restrict__ vf,
                                               const int* __restrict__ node_ids,
                                               const int* __restrict__ sent_ids,
                                               const int* __restrict__ rep,
                                               const int* __restrict__ nrec,
                                               const int* __restrict__ cnts,
                                               const int* __restrict__ recbuf,
                                               float* __restrict__ Xws,
                                               float* __restrict__ XAws,
                                               float* __restrict__ pv,
                                               float* __restrict__ qv) {
    int bl = blockIdx.x;
    int b  = bl / LL;
    int t  = threadIdx.x;
    const int* nid = node_ids + (size_t)b * NN;

    __shared__ float xsum[RR][DD];
    __shared__ float xnode[DD];
    __shared__ float xrow[DD];
    __shared__ int   recs[RECCAP];
    __shared__ int   csh[RR];

    int myrep = rep[bl];
    int nm = nrec[b];
    for (int i = t; i < RR * DD; i += 256) ((float*)xsum)[i] = 0.f;
    if (t < DD) xnode[t] = emb[(size_t)nid[sent_ids[bl]] * DD + t];
    if (t < RR) csh[t] = cnts[b * LL * RR + myrep * RR + t];
    for (int i = t; i < nm; i += 256) recs[i] = recbuf[b * RECCAP + i];
    __syncthreads();

    for (int m = 0; m < nm; ++m) {
        int rc = recs[m];
        if ((rc >> 14) != myrep) continue;
        int r = (rc >> 11) & 7;
        int s = rc & 2047;
        if (t < DD) xsum[r][t] += emb[(size_t)nid[s] * DD + t];
    }
    __syncthreads();

    if (t < DD) {
        float acc = root_b[t];
        float a = 0.f;
#pragma unroll 8
        for (int k = 0; k < DD; ++k) a = fmaf(xnode[k], root_w[k * DD + t], a);
        acc += a;
#pragma unroll
        for (int r = 0; r < RR; ++r) {
            int c = csh[r];
            if (c > 0) {
                const float* Wr = W + r * DD * DD;
                float a2 = 0.f;
#pragma unroll 8
                for (int k = 0; k < DD; ++k) a2 = fmaf(xsum[r][k], Wr[k * DD + t], a2);
                acc += a2 / (float)c;
            }
        }
        xrow[t] = acc;
        Xws[(size_t)bl * DD + t] = acc;
    }
    __syncthreads();

    if (t < DD) {
        float xa = 0.f;
#pragma unroll 8
        for (int k = 0; k < DD; ++k) xa = fmaf(xrow[k], A[k * DD + t], xa);
        XAws[(size_t)bl * DD + t] = xa;
    } else if (t < DD + 64) {
        int lane = t - DD;
        float pp = xrow[lane] * va[lane] + xrow[lane + 64] * va[lane + 64];
#pragma unroll
        for (int off = 32; off; off >>= 1) pp += __shfl_xor(pp, off);
        if (lane == 0) pv[bl] = pp;
    } else {
        int lane = t - DD - 64;
        float qq = xrow[lane] * vf[lane] + xrow[lane + 64] * vf[lane + 64];
#pragma unroll
        for (int off = 32; off; off >>= 1) qq += __shfl_xor(qq, off);
        if (lane == 0) qv[bl] = qq;
    }
}

// ---------------------------------------------------------------------------
// attn_row: one wave per (b,l). Score row, softmax, accumulate av*gv into acc[b].
// ---------------------------------------------------------------------------
__global__ __launch_bounds__(64) void attn_row(const float* __restrict__ Xws,
                                               const float* __restrict__ XAws,
                                               const float* __restrict__ pv,
                                               const float* __restrict__ qv,
                                               const float* __restrict__ attn_b,
                                               float* __restrict__ acc) {
    int bl = blockIdx.x;
    int b  = bl / LL;
    int lane = threadIdx.x;
    const float* Xb = Xws + (size_t)b * LL * DD;
    const float* xa = XAws + (size_t)bl * DD;
    float xa0 = xa[lane], xa1 = xa[lane + 64];

    float myS = 0.f;
    for (int m = 0; m < LL; m += 2) {
        const float* xm0 = Xb + m * DD;
        const float* xm1 = xm0 + DD;
        float p0 = xa0 * xm0[lane] + xa1 * xm0[lane + 64];
        float p1 = xa0 * xm1[lane] + xa1 * xm1[lane + 64];
#pragma unroll
        for (int off = 32; off; off >>= 1) {
            p0 += __shfl_xor(p0, off);
            p1 += __shfl_xor(p1, off);
        }
        if (lane == m)     myS = p0;
        if (lane == m + 1) myS = p1;
    }
    const float scale = 0.07216878364870322f;  // 1/sqrt(192)
    float sval = (lane < LL) ? myS * scale : -INFINITY;
    float mx = sval;
#pragma unroll
    for (int off = 32; off; off >>= 1) mx = fmaxf(mx, __shfl_xor(mx, off));
    float e = (lane < LL) ? __expf(sval - mx) : 0.f;
    float sum = e;
#pragma unroll
    for (int off = 32; off; off >>= 1) sum += __shfl_xor(sum, off);
    float inv = 1.f / sum;
    float sm = e * inv;
    float pa = (lane < LL) ? sm * pv[b * LL + lane] : 0.f;
    float qa = (lane < LL) ? sm * qv[b * LL + lane] : 0.f;
#pragma unroll
    for (int off = 32; off; off >>= 1) {
        pa += __shfl_xor(pa, off);
        qa += __shfl_xor(qa, off);
    }
    if (lane == 0) atomicAdd(&acc[b], (pa + attn_b[0]) * qa);
}

// ---------------------------------------------------------------------------
__global__ __launch_bounds__(64) void finalize(const float* __restrict__ acc,
                                               const float* __restrict__ fc_b,
                                               float* __restrict__ out) {
    int b = threadIdx.x;
    if (b < BDIM) out[b] = 1.f / (1.f + expf(-(acc[b] + fc_b[0])));
}

// ---------------------------------------------------------------------------
extern "C" void kernel_launch(void* const* d_in, const int* in_sizes, int n_in,
                              void* d_out, int out_size, void* d_ws, size_t ws_size,
                              hipStream_t stream) {
    const float* emb     = (const float*)d_in[0];
    const float* bases   = (const float*)d_in[1];
    const float* comp    = (const float*)d_in[2];
    const float* root_w  = (const float*)d_in[3];
    const float* root_b  = (const float*)d_in[4];
    const float* wq      = (const float*)d_in[5];
    const float* wk      = (const float*)d_in[6];
    const float* wv      = (const float*)d_in[7];
    const float* attn_w  = (const float*)d_in[8];
    const float* attn_b  = (const float*)d_in[9];
    const float* fc_w    = (const float*)d_in[10];
    const float* fc_b    = (const float*)d_in[11];
    const int* node_ids  = (const int*)d_in[12];
    const int* edge_index= (const int*)d_in[13];
    const int* edge_type = (const int*)d_in[14];
    const int* sent_ids  = (const int*)d_in[15];
    float* out = (float*)d_out;

    float* ws = (float*)d_ws;
    float* W    = ws;                       // 81920
    float* A    = ws + 81920;               // 16384
    float* va   = ws + 98304;               // 128
    float* vf   = ws + 98432;               // 128
    float* acc  = ws + 98560;               // 64
    float* pv   = ws + 98624;               // 3200
    float* qv   = ws + 101824;              // 3200
    float* Xws  = ws + 105024;              // 409600
    float* XAws = ws + 514624;              // 409600
    int*   rep    = (int*)(ws + 924224);    // 3200
    int*   nrec   = (int*)(ws + 927424);    // 64
    int*   cnts   = (int*)(ws + 927488);    // 16000
    int*   recbuf = (int*)(ws + 943488);    // 65536
    // total 1009024 elems = ~4.0 MB

    hipLaunchKernelGGL(precompute_W, dim3((RR * DD * DD + 255) / 256), dim3(256), 0, stream,
                       comp, bases, W);
    hipLaunchKernelGGL(precompute_A, dim3(DD), dim3(128), 0, stream, wq, wk, A);
    hipLaunchKernelGGL(precompute_v, dim3(1), dim3(128), 0, stream,
                       wv, attn_w, fc_w, va, vf, acc);
    hipLaunchKernelGGL(matchscan, dim3(BDIM), dim3(256), 0, stream,
                       edge_index, edge_type, sent_ids, rep, nrec, cnts, recbuf);
    hipLaunchKernelGGL(build_X, dim3(BDIM * LL), dim3(256), 0, stream,
                       emb, W, root_w, root_b, A, va, vf, node_ids, sent_ids,
                       rep, nrec, cnts, recbuf, Xws, XAws, pv, qv);
    hipLaunchKernelGGL(attn_row, dim3(BDIM * LL), dim3(64), 0, stream,
                       Xws, XAws, pv, qv, attn_b, acc);
    hipLaunchKernelGGL(finalize, dim3(1), dim3(64), 0, stream, acc, fc_b, out);
}

// Round 4
// 212.871 us; speedup vs baseline: 1.4311x; 1.1511x over previous
//
#include <hip/hip_runtime.h>
#include <math.h>

#define BDIM 64
#define NN   2048
#define EE   8192
#define LL   50
#define DD   128
#define RR   5
#define NBASES 4
#define H3   192
#define RECCAP 1024
#define KDIM 768          // 128 (root) + 5*128 (relations)
#define GROWS 16          // rows per gemm block

__device__ __forceinline__ void fma4(float4& a, float s, const float4& w) {
    a.x = fmaf(s, w.x, a.x); a.y = fmaf(s, w.y, a.y);
    a.z = fmaf(s, w.z, a.z); a.w = fmaf(s, w.w, a.w);
}

// ---------------------------------------------------------------------------
// K1: all small precomputes in one launch.
//   blocks [0,384):   Wcat[768][128] = [root_w ; W_r = comp.bases]
//   blocks [384,512): A[i][j] = wq[i]·wk[j]
//   block  512:       va/vf = wv·attn_w / wv·fc_w ; zero acc[64]
// ---------------------------------------------------------------------------
__global__ __launch_bounds__(256) void precompute_all(
        const float* __restrict__ bases, const float* __restrict__ comp,
        const float* __restrict__ root_w, const float* __restrict__ wq,
        const float* __restrict__ wk, const float* __restrict__ wv,
        const float* __restrict__ attn_w, const float* __restrict__ fc_w,
        float* __restrict__ Wcat, float* __restrict__ A,
        float* __restrict__ va, float* __restrict__ vf, float* __restrict__ acc) {
    int blk = blockIdx.x, t = threadIdx.x;
    if (blk < 384) {
        int idx = blk * 256 + t;              // < 98304 = 768*128
        int k = idx >> 7, o = idx & 127;
        if (k < DD) {
            Wcat[idx] = root_w[idx];
        } else {
            int r = (k - DD) >> 7, i = (k - DD) & 127;
            float s = 0.f;
#pragma unroll
            for (int bb = 0; bb < NBASES; ++bb)
                s += comp[r * NBASES + bb] * bases[bb * DD * DD + i * DD + o];
            Wcat[idx] = s;
        }
    } else if (blk < 512) {
        int i = blk - 384;
        __shared__ float wqs[H3];
        if (t < H3) wqs[t] = wq[i * H3 + t];
        __syncthreads();
        if (t < DD) {
            const float4* wkr = (const float4*)(wk + t * H3);
            float s = 0.f;
#pragma unroll
            for (int d4 = 0; d4 < H3 / 4; ++d4) {
                float4 v = wkr[d4];
                s += wqs[4*d4]*v.x + wqs[4*d4+1]*v.y + wqs[4*d4+2]*v.z + wqs[4*d4+3]*v.w;
            }
            A[i * DD + t] = s;
        }
    } else {
        if (t < DD) {
            const float4* wr = (const float4*)(wv + t * H3);
            float a = 0.f, f = 0.f;
#pragma unroll
            for (int d4 = 0; d4 < H3 / 4; ++d4) {
                float4 v = wr[d4];
                a += v.x*attn_w[4*d4] + v.y*attn_w[4*d4+1] + v.z*attn_w[4*d4+2] + v.w*attn_w[4*d4+3];
                f += v.x*fc_w[4*d4] + v.y*fc_w[4*d4+1] + v.z*fc_w[4*d4+2] + v.w*fc_w[4*d4+3];
            }
            va[t] = a; vf[t] = f;
        } else if (t < DD + BDIM) {
            acc[t - DD] = 0.f;
        }
    }
}

// ---------------------------------------------------------------------------
// K2: matchseg — one block per batch. Scan edges once, bucket matches by
// (l,r) with an LDS prefix sum -> segmented recbuf2 + segoff[b][251].
// ---------------------------------------------------------------------------
__global__ __launch_bounds__(512) void matchseg(const int* __restrict__ edge_index,
                                                const int* __restrict__ edge_type,
                                                const int* __restrict__ sent_ids,
                                                int* __restrict__ rep,
                                                int* __restrict__ segoff,
                                                int* __restrict__ recbuf2) {
    int b = blockIdx.x, t = threadIdx.x;
    __shared__ int mark[NN];
    __shared__ int scnt[LL * RR];
    __shared__ int soff[LL * RR + 1];
    __shared__ int scan[256];
    __shared__ int recs[RECCAP];
    __shared__ int lcnt;

    for (int i = t; i < NN; i += 512) mark[i] = -1;
    if (t < LL * RR) scnt[t] = 0;
    if (t == 0) lcnt = 0;
    __syncthreads();
    const int* sb = sent_ids + b * LL;
    if (t < LL) mark[sb[t]] = t;            // duplicates: arbitrary but consistent winner
    __syncthreads();
    if (t < LL) rep[b * LL + t] = mark[sb[t]];

    const int* src_arr = edge_index + (size_t)b * 2 * EE;
    const int* tgt_arr = src_arr + EE;
    const int* et_arr  = edge_type + (size_t)b * EE;
    const int4* tgt4 = (const int4*)tgt_arr;
    for (int i4 = t; i4 < EE / 4; i4 += 512) {
        int4 v = tgt4[i4];
        int e0 = 4 * i4;
        int lv[4] = {mark[v.x], mark[v.y], mark[v.z], mark[v.w]};
#pragma unroll
        for (int k = 0; k < 4; ++k) {
            int l = lv[k];
            if (l >= 0) {
                int e = e0 + k;
                int r = et_arr[e];
                int s = src_arr[e];
                int pos = atomicAdd(&lcnt, 1);
                if (pos < RECCAP) {
                    recs[pos] = (l << 14) | (r << 11) | s;
                    atomicAdd(&scnt[l * RR + r], 1);
                }
            }
        }
    }
    __syncthreads();
    // inclusive scan of scnt[0..249] over 256 lanes (Hillis-Steele)
    if (t < 256) scan[t] = (t < LL * RR) ? scnt[t] : 0;
    __syncthreads();
    for (int off = 1; off < 256; off <<= 1) {
        int v = 0;
        if (t < 256 && t >= off) v = scan[t - off];
        __syncthreads();
        if (t < 256) scan[t] += v;
        __syncthreads();
    }
    if (t == 0) soff[0] = 0;
    if (t < LL * RR) soff[t + 1] = scan[t];
    // reset cursors
    if (t < LL * RR) scnt[t] = 0;
    __syncthreads();
    if (t <= LL * RR) segoff[b * (LL * RR + 1) + t] = soff[t];
    int nm = (lcnt < RECCAP) ? lcnt : RECCAP;
    for (int i = t; i < nm; i += 512) {
        int rc = recs[i];
        int key = (rc >> 14) * RR + ((rc >> 11) & 7);
        int pos = soff[key] + atomicAdd(&scnt[key], 1);
        recbuf2[b * RECCAP + pos] = rc;
    }
}

// ---------------------------------------------------------------------------
// K3: aggregate — one wave per (b,l). Gather xnode + per-relation mean sums
// from the segmented record list, write U row [xnode | xsum_r / c_r] (K=768).
// ---------------------------------------------------------------------------
__global__ __launch_bounds__(64) void aggregate(const float* __restrict__ emb,
                                                const int* __restrict__ node_ids,
                                                const int* __restrict__ sent_ids,
                                                const int* __restrict__ rep,
                                                const int* __restrict__ segoff,
                                                const int* __restrict__ recbuf2,
                                                float* __restrict__ U) {
    int bl = blockIdx.x;
    int b  = bl / LL;
    int lane = threadIdx.x;
    const int* nid = node_ids + (size_t)b * NN;
    int myrep = rep[bl];
    const int* so = segoff + b * (LL * RR + 1) + myrep * RR;
    const int* rb = recbuf2 + b * RECCAP;
    float* Urow = U + (size_t)bl * KDIM;

    int row = nid[sent_ids[bl]];
    Urow[lane]      = emb[(size_t)row * DD + lane];
    Urow[lane + 64] = emb[(size_t)row * DD + 64 + lane];

#pragma unroll
    for (int r = 0; r < RR; ++r) {
        int s0 = so[r], s1 = so[r + 1];
        float a0 = 0.f, a1 = 0.f;
        for (int j = s0; j < s1; ++j) {
            int s = rb[j] & 2047;
            int rw = nid[s];
            a0 += emb[(size_t)rw * DD + lane];
            a1 += emb[(size_t)rw * DD + 64 + lane];
        }
        float inv = (s1 > s0) ? 1.f / (float)(s1 - s0) : 0.f;
        Urow[DD + r * DD + lane]      = a0 * inv;
        Urow[DD + r * DD + 64 + lane] = a1 * inv;
    }
}

// ---------------------------------------------------------------------------
// K4: gemm_fused — 16 rows/block, 256 threads (8 row-groups x 32 col-groups,
// 2x4 register tile). X = U@Wcat + root_b ; XA = X@A ; p = X·va ; q = X·vf.
// ---------------------------------------------------------------------------
__global__ __launch_bounds__(256) void gemm_fused(const float* __restrict__ U,
                                                  const float* __restrict__ Wcat,
                                                  const float* __restrict__ A,
                                                  const float* __restrict__ root_b,
                                                  const float* __restrict__ va,
                                                  const float* __restrict__ vf,
                                                  float* __restrict__ Xws,
                                                  float* __restrict__ XAws,
                                                  float* __restrict__ pv,
                                                  float* __restrict__ qv) {
    __shared__ float Us[GROWS][KDIM];      // 48 KB
    __shared__ float Xs[GROWS][DD];        // 8 KB
    __shared__ float vas[DD], vfs[DD];

    int t = threadIdx.x;
    int row0 = blockIdx.x * GROWS;
    int tx = t & 31, ty = t >> 5;          // ty 0..7
    int m0 = 2 * ty, m1 = m0 + 1;
    int c0 = 4 * tx;

    const float4* Ug = (const float4*)(U + (size_t)row0 * KDIM);
    for (int i = t; i < GROWS * KDIM / 4; i += 256) ((float4*)Us)[i] = Ug[i];
    if (t < DD) { vas[t] = va[t]; vfs[t] = vf[t]; }
    __syncthreads();

    float4 rb = *(const float4*)(root_b + c0);
    float4 acc0 = rb, acc1 = rb;
    const float4* Wc4 = (const float4*)Wcat;
    const float4* u0p = (const float4*)Us[m0];
    const float4* u1p = (const float4*)Us[m1];
#pragma unroll 2
    for (int k4 = 0; k4 < KDIM / 4; ++k4) {
        float4 u0 = u0p[k4], u1 = u1p[k4];
        int k = 4 * k4;
        float4 w0 = Wc4[(k + 0) * 32 + tx];
        float4 w1 = Wc4[(k + 1) * 32 + tx];
        float4 w2 = Wc4[(k + 2) * 32 + tx];
        float4 w3 = Wc4[(k + 3) * 32 + tx];
        fma4(acc0, u0.x, w0); fma4(acc1, u1.x, w0);
        fma4(acc0, u0.y, w1); fma4(acc1, u1.y, w1);
        fma4(acc0, u0.z, w2); fma4(acc1, u1.z, w2);
        fma4(acc0, u0.w, w3); fma4(acc1, u1.w, w3);
    }
    *(float4*)&Xs[m0][c0] = acc0;
    *(float4*)&Xs[m1][c0] = acc1;
    *(float4*)(Xws + (size_t)(row0 + m0) * DD + c0) = acc0;
    *(float4*)(Xws + (size_t)(row0 + m1) * DD + c0) = acc1;
    __syncthreads();

    // XA = X @ A
    float4 z0 = {0,0,0,0}, z1 = {0,0,0,0};
    const float4* A4 = (const float4*)A;
    const float4* x0p = (const float4*)Xs[m0];
    const float4* x1p = (const float4*)Xs[m1];
#pragma unroll 2
    for (int k4 = 0; k4 < DD / 4; ++k4) {
        float4 x0 = x0p[k4], x1 = x1p[k4];
        int k = 4 * k4;
        float4 a0 = A4[(k + 0) * 32 + tx];
        float4 a1 = A4[(k + 1) * 32 + tx];
        float4 a2 = A4[(k + 2) * 32 + tx];
        float4 a3 = A4[(k + 3) * 32 + tx];
        fma4(z0, x0.x, a0); fma4(z1, x1.x, a0);
        fma4(z0, x0.y, a1); fma4(z1, x1.y, a1);
        fma4(z0, x0.z, a2); fma4(z1, x1.z, a2);
        fma4(z0, x0.w, a3); fma4(z1, x1.w, a3);
    }
    *(float4*)(XAws + (size_t)(row0 + m0) * DD + c0) = z0;
    *(float4*)(XAws + (size_t)(row0 + m1) * DD + c0) = z1;

    // p/q: wave w handles rows 4w..4w+3
    int lane = t & 63, w = t >> 6;
#pragma unroll
    for (int rr = 0; rr < 4; ++rr) {
        int m = 4 * w + rr;
        float xv0 = Xs[m][lane], xv1 = Xs[m][lane + 64];
        float pp = xv0 * vas[lane] + xv1 * vas[lane + 64];
        float qq = xv0 * vfs[lane] + xv1 * vfs[lane + 64];
#pragma unroll
        for (int off = 32; off; off >>= 1) {
            pp += __shfl_xor(pp, off);
            qq += __shfl_xor(qq, off);
        }
        if (lane == 0) { pv[row0 + m] = pp; qv[row0 + m] = qq; }
    }
}

// ---------------------------------------------------------------------------
// K5: attn_row — one wave per (b,l): score row, softmax, acc[b] += av*gv.
// ---------------------------------------------------------------------------
__global__ __launch_bounds__(64) void attn_row(const float* __restrict__ Xws,
                                               const float* __restrict__ XAws,
                                               const float* __restrict__ pv,
                                               const float* __restrict__ qv,
                                               const float* __restrict__ attn_b,
                                               float* __restrict__ acc) {
    int bl = blockIdx.x;
    int b  = bl / LL;
    int lane = threadIdx.x;
    const float* Xb = Xws + (size_t)b * LL * DD;
    const float* xa = XAws + (size_t)bl * DD;
    float xa0 = xa[lane], xa1 = xa[lane + 64];

    float myS = 0.f;
    for (int m = 0; m < LL; m += 2) {
        const float* xm0 = Xb + m * DD;
        const float* xm1 = xm0 + DD;
        float p0 = xa0 * xm0[lane] + xa1 * xm0[lane + 64];
        float p1 = xa0 * xm1[lane] + xa1 * xm1[lane + 64];
#pragma unroll
        for (int off = 32; off; off >>= 1) {
            p0 += __shfl_xor(p0, off);
            p1 += __shfl_xor(p1, off);
        }
        if (lane == m)     myS = p0;
        if (lane == m + 1) myS = p1;
    }
    const float scale = 0.07216878364870322f;  // 1/sqrt(192)
    float sval = (lane < LL) ? myS * scale : -INFINITY;
    float mx = sval;
#pragma unroll
    for (int off = 32; off; off >>= 1) mx = fmaxf(mx, __shfl_xor(mx, off));
    float e = (lane < LL) ? __expf(sval - mx) : 0.f;
    float sum = e;
#pragma unroll
    for (int off = 32; off; off >>= 1) sum += __shfl_xor(sum, off);
    float inv = 1.f / sum;
    float sm = e * inv;
    float pa = (lane < LL) ? sm * pv[b * LL + lane] : 0.f;
    float qa = (lane < LL) ? sm * qv[b * LL + lane] : 0.f;
#pragma unroll
    for (int off = 32; off; off >>= 1) {
        pa += __shfl_xor(pa, off);
        qa += __shfl_xor(qa, off);
    }
    if (lane == 0) atomicAdd(&acc[b], (pa + attn_b[0]) * qa);
}

// ---------------------------------------------------------------------------
__global__ __launch_bounds__(64) void finalize(const float* __restrict__ acc,
                                               const float* __restrict__ fc_b,
                                               float* __restrict__ out) {
    int b = threadIdx.x;
    if (b < BDIM) out[b] = 1.f / (1.f + expf(-(acc[b] + fc_b[0])));
}

// ---------------------------------------------------------------------------
extern "C" void kernel_launch(void* const* d_in, const int* in_sizes, int n_in,
                              void* d_out, int out_size, void* d_ws, size_t ws_size,
                              hipStream_t stream) {
    const float* emb     = (const float*)d_in[0];
    const float* bases   = (const float*)d_in[1];
    const float* comp    = (const float*)d_in[2];
    const float* root_w  = (const float*)d_in[3];
    const float* root_b  = (const float*)d_in[4];
    const float* wq      = (const float*)d_in[5];
    const float* wk      = (const float*)d_in[6];
    const float* wv      = (const float*)d_in[7];
    const float* attn_w  = (const float*)d_in[8];
    const float* attn_b  = (const float*)d_in[9];
    const float* fc_w    = (const float*)d_in[10];
    const float* fc_b    = (const float*)d_in[11];
    const int* node_ids  = (const int*)d_in[12];
    const int* edge_index= (const int*)d_in[13];
    const int* edge_type = (const int*)d_in[14];
    const int* sent_ids  = (const int*)d_in[15];
    float* out = (float*)d_out;

    float* ws = (float*)d_ws;
    float* Wcat = ws;                         // 98304
    float* A    = ws + 98304;                 // 16384
    float* va   = ws + 114688;                // 128
    float* vf   = ws + 114816;                // 128
    float* acc  = ws + 114944;                // 64
    float* pv   = ws + 115008;                // 3200
    float* qv   = ws + 118208;                // 3200
    float* Xws  = ws + 121408;                // 409600
    float* XAws = ws + 531008;                // 409600
    float* U    = ws + 940608;                // 3200*768 = 2457600
    int* rep     = (int*)(ws + 3398208);      // 3200
    int* segoff  = (int*)(ws + 3401408);      // 64*251 = 16064
    int* recbuf2 = (int*)(ws + 3417472);      // 65536
    // total ~3.48M elems = ~13.3 MiB

    hipLaunchKernelGGL(precompute_all, dim3(513), dim3(256), 0, stream,
                       bases, comp, root_w, wq, wk, wv, attn_w, fc_w,
                       Wcat, A, va, vf, acc);
    hipLaunchKernelGGL(matchseg, dim3(BDIM), dim3(512), 0, stream,
                       edge_index, edge_type, sent_ids, rep, segoff, recbuf2);
    hipLaunchKernelGGL(aggregate, dim3(BDIM * LL), dim3(64), 0, stream,
                       emb, node_ids, sent_ids, rep, segoff, recbuf2, U);
    hipLaunchKernelGGL(gemm_fused, dim3(BDIM * LL / GROWS), dim3(256), 0, stream,
                       U, Wcat, A, root_b, va, vf, Xws, XAws, pv, qv);
    hipLaunchKernelGGL(attn_row, dim3(BDIM * LL), dim3(64), 0, stream,
                       Xws, XAws, pv, qv, attn_b, acc);
    hipLaunchKernelGGL(finalize, dim3(1), dim3(64), 0, stream, acc, fc_b, out);
}